// Round 1
// baseline (520.792 us; speedup 1.0000x reference)
//
#include <hip/hip_runtime.h>

// ---------------------------------------------------------------------------
// UpsampleLayer: out = Upsample2x_FIR( W @ x ) + bias   (upsample and 1x1 conv
// commute, so the GEMM runs at 64x64 instead of 127x127 -> 4x fewer FLOPs).
//
// Shapes: x[16][512][64][64] f32, w[512][512] f32, bias[512] f32 (zeros),
//         out[16][512][127][127] f32.
// Upsample (derived from lax.conv_general_dilated, lhs_dilation=2, pad=(2,1),
// kernel outer([1,3,3,1],[1,3,3,1])/16):
//   y[2m]   = (3*z[m] + z[m-1]) / 4      (z[-1] = 0)
//   y[2m+1] = (3*z[m] + z[m+1]) / 4
// per axis; output spatial size = 127.
// ---------------------------------------------------------------------------

#define B_   16
#define CIN  512
#define COUT 512
#define S_   4096   // 64*64
#define HO   127
#define WO   127

typedef unsigned int  u32;
typedef unsigned short u16;
typedef __attribute__((ext_vector_type(8))) short  bf16x8;
typedef __attribute__((ext_vector_type(8))) u16    u16x8;
typedef __attribute__((ext_vector_type(4))) float  f32x4;

static __device__ __forceinline__ u16 f2bf(float f) {
  u32 u = __float_as_uint(f);
  u += 0x7FFFu + ((u >> 16) & 1u);   // round-to-nearest-even (inputs finite)
  return (u16)(u >> 16);
}
static __device__ __forceinline__ float bf2f(u16 h) {
  return __uint_as_float(((u32)h) << 16);
}

#if defined(__has_builtin)
#if __has_builtin(__builtin_amdgcn_global_load_lds)
#define HAS_GLOAD 1
#endif
#endif
#ifndef HAS_GLOAD
#define HAS_GLOAD 0
#endif

#if HAS_GLOAD
static __device__ __forceinline__ void gload16(const char* g, char* l) {
  __builtin_amdgcn_global_load_lds(
      (const __attribute__((address_space(1))) unsigned int*)g,
      (__attribute__((address_space(3))) unsigned int*)l, 16, 0, 0);
}
#endif

// ---------------------------------------------------------------------------
// Tiled operand layout (both W and X^T), per 128(row) x 32(k) tile = 8 KiB:
//   tile = 512 units of 16B; unit u = kg*128 + r  (kg = (k%32)/8, r = row%128)
//   unit contents = 8 bf16, k = k0 + kg*8 + e.
// This is exactly the LDS image the GEMM wants: fragment read for lane l is
// unit (l>>4)*128 + fragrow*16 + (l&15)  -> consecutive lanes, consecutive
// 16B units -> conflict-free ds_read_b128; staging = contiguous
// global_load_lds dwordx4.
// ---------------------------------------------------------------------------

// w[o][c] f32 -> wt tiled bf16. 32768 units total.
__global__ __launch_bounds__(256) void conv_w_kernel(
    const float* __restrict__ w, u16* __restrict__ wt) {
  int g = blockIdx.x * 256 + threadIdx.x;  // unit index
  int t_idx = g >> 9;                      // tile index (to*16 + tk)
  int u = g & 511;
  int to = t_idx >> 4, tk = t_idx & 15;
  int r = u & 127, kg = u >> 7;
  int o = to * 128 + r;
  int c = tk * 32 + kg * 8;
  const float4* src = reinterpret_cast<const float4*>(w + (size_t)o * CIN + c);
  float4 lo = src[0], hi = src[1];
  u16x8 pk;
  pk[0] = f2bf(lo.x); pk[1] = f2bf(lo.y); pk[2] = f2bf(lo.z); pk[3] = f2bf(lo.w);
  pk[4] = f2bf(hi.x); pk[5] = f2bf(hi.y); pk[6] = f2bf(hi.z); pk[7] = f2bf(hi.w);
  *reinterpret_cast<u16x8*>(wt + (size_t)g * 8) = pk;
}

// x[b][c][s] f32 -> xt tiled bf16 with (s,c) transpose.
// block = (ts, tk, b): 128 s-cols x 32 c-rows.
__global__ __launch_bounds__(256) void conv_x_kernel(
    const float* __restrict__ x, u16* __restrict__ xt) {
  int ts = blockIdx.x, tk = blockIdx.y, b = blockIdx.z;
  int t = threadIdx.x;
  __shared__ float lf[32 * 128];
  const float* src = x + ((size_t)(b * CIN + tk * 32)) * S_ + ts * 128;
#pragma unroll
  for (int i = 0; i < 4; ++i) {  // 1024 float4 total
    int q = i * 256 + t;
    int c = q >> 5, sq = q & 31;
    *reinterpret_cast<float4*>(&lf[c * 128 + sq * 4]) =
        *reinterpret_cast<const float4*>(src + (size_t)c * S_ + sq * 4);
  }
  __syncthreads();
  size_t tile_base = (((size_t)(b * 32 + ts)) * 16 + tk) * 512;  // in units
#pragma unroll
  for (int i = 0; i < 2; ++i) {
    int u = i * 256 + t;
    int kg = u >> 7, r = u & 127;
    u16x8 pk;
#pragma unroll
    for (int e = 0; e < 8; ++e) pk[e] = f2bf(lf[(kg * 8 + e) * 128 + r]);
    *reinterpret_cast<u16x8*>(xt + (tile_base + u) * 8) = pk;
  }
}

// GEMM: Z[b][o][s] = sum_c W[o][c] * X[b][c][s], 128x128 tile, BK=32,
// 4 waves (2x2), each wave 64x64 = 4x4 frags of mfma_f32_16x16x32_bf16.
__global__ __launch_bounds__(256) void gemm_kernel(
    const u16* __restrict__ wt, const u16* __restrict__ xt,
    u16* __restrict__ z) {
  int nt = blockIdx.x, mt = blockIdx.y, b = blockIdx.z;
  int t = threadIdx.x;
  __shared__ short lds[8192];  // A: bytes [0,8192), B: bytes [8192,16384)
  char* lA = (char*)&lds[0];
  char* lB = lA + 8192;

  int lane = t & 63, wid = t >> 6;
  int wr = wid >> 1, wc = wid & 1;
  int lr = lane & 15, kg = lane >> 4;

  f32x4 acc[4][4];
#pragma unroll
  for (int m = 0; m < 4; ++m)
#pragma unroll
    for (int n = 0; n < 4; ++n) acc[m][n] = f32x4{0.f, 0.f, 0.f, 0.f};

  const char* gA = (const char*)wt + (size_t)(mt * 16) * 8192;
  const char* gB = (const char*)xt + ((size_t)(b * 32 + nt)) * 16 * 8192;

  int abyte[4], bbyte[4];
#pragma unroll
  for (int m = 0; m < 4; ++m) abyte[m] = (kg * 128 + wr * 64 + m * 16 + lr) * 16;
#pragma unroll
  for (int n = 0; n < 4; ++n) bbyte[n] = (kg * 128 + wc * 64 + n * 16 + lr) * 16;

  for (int ks = 0; ks < 16; ++ks) {
    const char* pA = gA + (size_t)ks * 8192;
    const char* pB = gB + (size_t)ks * 8192;
#if HAS_GLOAD
    __syncthreads();  // previous compute done reading LDS
    gload16(pA + t * 16, lA + t * 16);
    gload16(pA + 4096 + t * 16, lA + 4096 + t * 16);
    gload16(pB + t * 16, lB + t * 16);
    gload16(pB + 4096 + t * 16, lB + 4096 + t * 16);
    __syncthreads();  // drains vmcnt, publishes LDS
#else
    u16x8 va0 = *reinterpret_cast<const u16x8*>(pA + t * 16);
    u16x8 va1 = *reinterpret_cast<const u16x8*>(pA + 4096 + t * 16);
    u16x8 vb0 = *reinterpret_cast<const u16x8*>(pB + t * 16);
    u16x8 vb1 = *reinterpret_cast<const u16x8*>(pB + 4096 + t * 16);
    __syncthreads();
    *reinterpret_cast<u16x8*>(lA + t * 16) = va0;
    *reinterpret_cast<u16x8*>(lA + 4096 + t * 16) = va1;
    *reinterpret_cast<u16x8*>(lB + t * 16) = vb0;
    *reinterpret_cast<u16x8*>(lB + 4096 + t * 16) = vb1;
    __syncthreads();
#endif
    bf16x8 av[4], bv[4];
#pragma unroll
    for (int m = 0; m < 4; ++m)
      av[m] = *reinterpret_cast<const bf16x8*>(lA + abyte[m]);
#pragma unroll
    for (int n = 0; n < 4; ++n)
      bv[n] = *reinterpret_cast<const bf16x8*>(lB + bbyte[n]);
#pragma unroll
    for (int m = 0; m < 4; ++m)
#pragma unroll
      for (int n = 0; n < 4; ++n)
        acc[m][n] = __builtin_amdgcn_mfma_f32_16x16x32_bf16(
            av[m], bv[n], acc[m][n], 0, 0, 0);
  }

  // C/D layout: col = lane&15 (s), row = (lane>>4)*4 + reg (o).
  int o_b = mt * 128 + wr * 64 + kg * 4;
  int s_b = nt * 128 + wc * 64 + lr;
#pragma unroll
  for (int m = 0; m < 4; ++m)
#pragma unroll
    for (int n = 0; n < 4; ++n) {
      f32x4 v = acc[m][n];
      size_t base = ((size_t)(b * COUT + o_b + m * 16)) * S_ + (s_b + n * 16);
#pragma unroll
      for (int r = 0; r < 4; ++r) z[base + (size_t)r * S_] = f2bf(v[r]);
    }
}

// Upsample z (bf16, [b*512][64][64]) by 2 with FIR taps + bias -> out f32.
__global__ __launch_bounds__(256) void upsample_kernel(
    const u16* __restrict__ z, const float* __restrict__ bias,
    float* __restrict__ out) {
  u32 idx = blockIdx.x * 256u + threadIdx.x;
  const u32 total = (u32)B_ * COUT * HO * WO;
  if (idx >= total) return;
  u32 j = idx % WO;
  u32 r1 = idx / WO;
  u32 i = r1 % HO;
  u32 bo = r1 / HO;  // b*512 + o
  int o = (int)(bo & 511u);
  const u16* zp = z + (size_t)bo * S_;
  int m = (int)(i >> 1), n = (int)(j >> 1);
  int ie = !(i & 1), je = !(j & 1);
  int rA = ie ? m - 1 : m;   // rows rA (w0), rA+1 (w1); rA+1 always in [0,63]
  int cA = je ? n - 1 : n;
  float w_r0 = ie ? 1.f : 3.f, w_r1 = ie ? 3.f : 1.f;
  float w_c0 = je ? 1.f : 3.f, w_c1 = je ? 3.f : 1.f;
  float a = 0.f;
  const u16* row0 = zp + rA * 64;
  const u16* row1 = row0 + 64;
  if (rA >= 0) {
    if (cA >= 0) a += w_r0 * w_c0 * bf2f(row0[cA]);
    a += w_r0 * w_c1 * bf2f(row0[cA + 1]);
  }
  if (cA >= 0) a += w_r1 * w_c0 * bf2f(row1[cA]);
  a += w_r1 * w_c1 * bf2f(row1[cA + 1]);
  out[idx] = a * 0.0625f + bias[o];
}

// Slow but correct fallback if ws_size is insufficient (no workspace needed).
__global__ __launch_bounds__(256) void fallback_kernel(
    const float* __restrict__ x, const float* __restrict__ w,
    const float* __restrict__ bias, float* __restrict__ out) {
  u32 idx = blockIdx.x * 256u + threadIdx.x;
  const u32 total = (u32)B_ * COUT * HO * WO;
  if (idx >= total) return;
  u32 j = idx % WO;
  u32 r1 = idx / WO;
  u32 i = r1 % HO;
  u32 bo = r1 / HO;
  int o = (int)(bo & 511u);
  int b = (int)(bo >> 9);
  int m = (int)(i >> 1), n = (int)(j >> 1);
  int ie = !(i & 1), je = !(j & 1);
  int rA = ie ? m - 1 : m;
  int cA = je ? n - 1 : n;
  float w_r0 = ie ? 1.f : 3.f, w_r1 = ie ? 3.f : 1.f;
  float w_c0 = je ? 1.f : 3.f, w_c1 = je ? 3.f : 1.f;
  const float* xb = x + (size_t)b * CIN * S_;
  float acc = 0.f;
  for (int c = 0; c < CIN; ++c) {
    const float* xc = xb + (size_t)c * S_;
    float y = 0.f;
    if (rA >= 0) {
      if (cA >= 0) y += w_r0 * w_c0 * xc[rA * 64 + cA];
      y += w_r0 * w_c1 * xc[rA * 64 + cA + 1];
    }
    if (cA >= 0) y += w_r1 * w_c0 * xc[(rA + 1) * 64 + cA];
    y += w_r1 * w_c1 * xc[(rA + 1) * 64 + cA + 1];
    acc += y * w[(size_t)o * CIN + c];
  }
  out[idx] = acc * 0.0625f + bias[o];
}

extern "C" void kernel_launch(void* const* d_in, const int* in_sizes, int n_in,
                              void* d_out, int out_size, void* d_ws,
                              size_t ws_size, hipStream_t stream) {
  const float* x = (const float*)d_in[0];
  // d_in[1] = fir_kernel (deterministic, hard-coded taps above)
  const float* w = (const float*)d_in[2];
  const float* bias = (const float*)d_in[3];
  float* out = (float*)d_out;

  const size_t xt_bytes = (size_t)B_ * S_ * CIN * 2;       // 64 MiB
  const size_t wt_off = xt_bytes;
  const size_t wt_bytes = (size_t)COUT * CIN * 2;          // 512 KiB
  const size_t z_off = wt_off + ((wt_bytes + 255) & ~(size_t)255);
  const size_t need = z_off + (size_t)B_ * COUT * S_ * 2;  // ~128.5 MiB
  const size_t total_out = (size_t)B_ * COUT * HO * WO;
  const u32 nblk_out = (u32)((total_out + 255) / 256);

  if (ws_size >= need) {
    u16* xt = (u16*)d_ws;
    u16* wt = (u16*)((char*)d_ws + wt_off);
    u16* zz = (u16*)((char*)d_ws + z_off);
    conv_w_kernel<<<128, 256, 0, stream>>>(w, wt);
    conv_x_kernel<<<dim3(32, 16, B_), 256, 0, stream>>>(x, xt);
    gemm_kernel<<<dim3(32, 4, B_), 256, 0, stream>>>(wt, xt, zz);
    upsample_kernel<<<nblk_out, 256, 0, stream>>>(zz, bias, out);
  } else {
    fallback_kernel<<<nblk_out, 256, 0, stream>>>(x, w, bias, out);
  }
}

// Round 2
// 351.478 us; speedup vs baseline: 1.4817x; 1.4817x over previous
//
#include <hip/hip_runtime.h>

// ---------------------------------------------------------------------------
// UpsampleLayer: out = Upsample2x_FIR( W @ x ) + bias   (upsample and 1x1 conv
// commute, so the GEMM runs at 64x64 instead of 127x127 -> 4x fewer FLOPs).
//
// Shapes: x[16][512][64][64] f32, w[512][512] f32, bias[512] f32 (zeros),
//         out[16][512][127][127] f32.
// Upsample (derived from lax.conv_general_dilated, lhs_dilation=2, pad=(2,1),
// kernel outer([1,3,3,1],[1,3,3,1])/16):
//   y[2m]   = (3*z[m] + z[m-1]) / 4      (z[-1] = 0)
//   y[2m+1] = (3*z[m] + z[m+1]) / 4
// per axis; output spatial size = 127.
// R1: upsample rewritten as one thread -> 2x2 output quad from one z cell:
// pow2 index math, separable FIR shared across the quad (was VALU-bound at
// 1.44 TB/s, 436 us).
// ---------------------------------------------------------------------------

#define B_   16
#define CIN  512
#define COUT 512
#define S_   4096   // 64*64
#define HO   127
#define WO   127

typedef unsigned int  u32;
typedef unsigned short u16;
typedef __attribute__((ext_vector_type(8))) short  bf16x8;
typedef __attribute__((ext_vector_type(8))) u16    u16x8;
typedef __attribute__((ext_vector_type(4))) float  f32x4;

static __device__ __forceinline__ u16 f2bf(float f) {
  u32 u = __float_as_uint(f);
  u += 0x7FFFu + ((u >> 16) & 1u);   // round-to-nearest-even (inputs finite)
  return (u16)(u >> 16);
}
static __device__ __forceinline__ float bf2f(u16 h) {
  return __uint_as_float(((u32)h) << 16);
}

#if defined(__has_builtin)
#if __has_builtin(__builtin_amdgcn_global_load_lds)
#define HAS_GLOAD 1
#endif
#endif
#ifndef HAS_GLOAD
#define HAS_GLOAD 0
#endif

#if HAS_GLOAD
static __device__ __forceinline__ void gload16(const char* g, char* l) {
  __builtin_amdgcn_global_load_lds(
      (const __attribute__((address_space(1))) unsigned int*)g,
      (__attribute__((address_space(3))) unsigned int*)l, 16, 0, 0);
}
#endif

// ---------------------------------------------------------------------------
// Tiled operand layout (both W and X^T), per 128(row) x 32(k) tile = 8 KiB:
//   tile = 512 units of 16B; unit u = kg*128 + r  (kg = (k%32)/8, r = row%128)
//   unit contents = 8 bf16, k = k0 + kg*8 + e.
// ---------------------------------------------------------------------------

// w[o][c] f32 -> wt tiled bf16. 32768 units total.
__global__ __launch_bounds__(256) void conv_w_kernel(
    const float* __restrict__ w, u16* __restrict__ wt) {
  int g = blockIdx.x * 256 + threadIdx.x;  // unit index
  int t_idx = g >> 9;                      // tile index (to*16 + tk)
  int u = g & 511;
  int to = t_idx >> 4, tk = t_idx & 15;
  int r = u & 127, kg = u >> 7;
  int o = to * 128 + r;
  int c = tk * 32 + kg * 8;
  const float4* src = reinterpret_cast<const float4*>(w + (size_t)o * CIN + c);
  float4 lo = src[0], hi = src[1];
  u16x8 pk;
  pk[0] = f2bf(lo.x); pk[1] = f2bf(lo.y); pk[2] = f2bf(lo.z); pk[3] = f2bf(lo.w);
  pk[4] = f2bf(hi.x); pk[5] = f2bf(hi.y); pk[6] = f2bf(hi.z); pk[7] = f2bf(hi.w);
  *reinterpret_cast<u16x8*>(wt + (size_t)g * 8) = pk;
}

// x[b][c][s] f32 -> xt tiled bf16 with (s,c) transpose.
// block = (ts, tk, b): 128 s-cols x 32 c-rows.
__global__ __launch_bounds__(256) void conv_x_kernel(
    const float* __restrict__ x, u16* __restrict__ xt) {
  int ts = blockIdx.x, tk = blockIdx.y, b = blockIdx.z;
  int t = threadIdx.x;
  __shared__ float lf[32 * 128];
  const float* src = x + ((size_t)(b * CIN + tk * 32)) * S_ + ts * 128;
#pragma unroll
  for (int i = 0; i < 4; ++i) {  // 1024 float4 total
    int q = i * 256 + t;
    int c = q >> 5, sq = q & 31;
    *reinterpret_cast<float4*>(&lf[c * 128 + sq * 4]) =
        *reinterpret_cast<const float4*>(src + (size_t)c * S_ + sq * 4);
  }
  __syncthreads();
  size_t tile_base = (((size_t)(b * 32 + ts)) * 16 + tk) * 512;  // in units
#pragma unroll
  for (int i = 0; i < 2; ++i) {
    int u = i * 256 + t;
    int kg = u >> 7, r = u & 127;
    u16x8 pk;
#pragma unroll
    for (int e = 0; e < 8; ++e) pk[e] = f2bf(lf[(kg * 8 + e) * 128 + r]);
    *reinterpret_cast<u16x8*>(xt + (tile_base + u) * 8) = pk;
  }
}

// GEMM: Z[b][o][s] = sum_c W[o][c] * X[b][c][s], 128x128 tile, BK=32,
// 4 waves (2x2), each wave 64x64 = 4x4 frags of mfma_f32_16x16x32_bf16.
__global__ __launch_bounds__(256) void gemm_kernel(
    const u16* __restrict__ wt, const u16* __restrict__ xt,
    u16* __restrict__ z) {
  int nt = blockIdx.x, mt = blockIdx.y, b = blockIdx.z;
  int t = threadIdx.x;
  __shared__ short lds[8192];  // A: bytes [0,8192), B: bytes [8192,16384)
  char* lA = (char*)&lds[0];
  char* lB = lA + 8192;

  int lane = t & 63, wid = t >> 6;
  int wr = wid >> 1, wc = wid & 1;
  int lr = lane & 15, kg = lane >> 4;

  f32x4 acc[4][4];
#pragma unroll
  for (int m = 0; m < 4; ++m)
#pragma unroll
    for (int n = 0; n < 4; ++n) acc[m][n] = f32x4{0.f, 0.f, 0.f, 0.f};

  const char* gA = (const char*)wt + (size_t)(mt * 16) * 8192;
  const char* gB = (const char*)xt + ((size_t)(b * 32 + nt)) * 16 * 8192;

  int abyte[4], bbyte[4];
#pragma unroll
  for (int m = 0; m < 4; ++m) abyte[m] = (kg * 128 + wr * 64 + m * 16 + lr) * 16;
#pragma unroll
  for (int n = 0; n < 4; ++n) bbyte[n] = (kg * 128 + wc * 64 + n * 16 + lr) * 16;

  for (int ks = 0; ks < 16; ++ks) {
    const char* pA = gA + (size_t)ks * 8192;
    const char* pB = gB + (size_t)ks * 8192;
#if HAS_GLOAD
    __syncthreads();  // previous compute done reading LDS
    gload16(pA + t * 16, lA + t * 16);
    gload16(pA + 4096 + t * 16, lA + 4096 + t * 16);
    gload16(pB + t * 16, lB + t * 16);
    gload16(pB + 4096 + t * 16, lB + 4096 + t * 16);
    __syncthreads();  // drains vmcnt, publishes LDS
#else
    u16x8 va0 = *reinterpret_cast<const u16x8*>(pA + t * 16);
    u16x8 va1 = *reinterpret_cast<const u16x8*>(pA + 4096 + t * 16);
    u16x8 vb0 = *reinterpret_cast<const u16x8*>(pB + t * 16);
    u16x8 vb1 = *reinterpret_cast<const u16x8*>(pB + 4096 + t * 16);
    __syncthreads();
    *reinterpret_cast<u16x8*>(lA + t * 16) = va0;
    *reinterpret_cast<u16x8*>(lA + 4096 + t * 16) = va1;
    *reinterpret_cast<u16x8*>(lB + t * 16) = vb0;
    *reinterpret_cast<u16x8*>(lB + 4096 + t * 16) = vb1;
    __syncthreads();
#endif
    bf16x8 av[4], bv[4];
#pragma unroll
    for (int m = 0; m < 4; ++m)
      av[m] = *reinterpret_cast<const bf16x8*>(lA + abyte[m]);
#pragma unroll
    for (int n = 0; n < 4; ++n)
      bv[n] = *reinterpret_cast<const bf16x8*>(lB + bbyte[n]);
#pragma unroll
    for (int m = 0; m < 4; ++m)
#pragma unroll
      for (int n = 0; n < 4; ++n)
        acc[m][n] = __builtin_amdgcn_mfma_f32_16x16x32_bf16(
            av[m], bv[n], acc[m][n], 0, 0, 0);
  }

  // C/D layout: col = lane&15 (s), row = (lane>>4)*4 + reg (o).
  int o_b = mt * 128 + wr * 64 + kg * 4;
  int s_b = nt * 128 + wc * 64 + lr;
#pragma unroll
  for (int m = 0; m < 4; ++m)
#pragma unroll
    for (int n = 0; n < 4; ++n) {
      f32x4 v = acc[m][n];
      size_t base = ((size_t)(b * COUT + o_b + m * 16)) * S_ + (s_b + n * 16);
#pragma unroll
      for (int r = 0; r < 4; ++r) z[base + (size_t)r * S_] = f2bf(v[r]);
    }
}

// R1 upsample: one thread computes the 2x2 output quad (2m,2n)..(2m+1,2n+1)
// from z cell (m,n) and its 3x3 neighborhood. All index math is pow2.
// 33.55M threads, 4B..16B written per thread.
__global__ __launch_bounds__(256) void upsample_kernel(
    const u16* __restrict__ z, const float* __restrict__ bias,
    float* __restrict__ out) {
  u32 idx = blockIdx.x * 256u + threadIdx.x;
  int n = (int)(idx & 63u);
  int m = (int)((idx >> 6) & 63u);
  u32 bo = idx >> 12;  // b*512 + o  (uniform per block: 4096 threads per bo)
  const u16* zp = z + ((size_t)bo << 12) + (m << 6) + n;
  float bv = bias[bo & 511u];

  bool up = (m > 0), dn = (m < 63), lf = (n > 0), rt = (n < 63);

  float z_mc = bf2f(zp[0]);
  float z_ml = lf ? bf2f(zp[-1]) : 0.f;
  float z_mr = rt ? bf2f(zp[1]) : 0.f;
  float z_uc = up ? bf2f(zp[-64]) : 0.f;
  float z_ul = (up && lf) ? bf2f(zp[-65]) : 0.f;
  float z_ur = (up && rt) ? bf2f(zp[-63]) : 0.f;
  float z_dc = dn ? bf2f(zp[64]) : 0.f;
  float z_dl = (dn && lf) ? bf2f(zp[63]) : 0.f;
  float z_dr = (dn && rt) ? bf2f(zp[65]) : 0.f;

  // horizontal FIR: hA -> even col 2n (taps 1,3 on n-1,n); hB -> odd col 2n+1
  float hA_u = fmaf(3.f, z_uc, z_ul);
  float hB_u = fmaf(3.f, z_uc, z_ur);
  float hA_m = fmaf(3.f, z_mc, z_ml);
  float hB_m = fmaf(3.f, z_mc, z_mr);
  float hA_d = fmaf(3.f, z_dc, z_dl);
  float hB_d = fmaf(3.f, z_dc, z_dr);

  // vertical FIR: even row 2m = 1*(m-1) + 3*m ; odd row 2m+1 = 3*m + 1*(m+1)
  float oEE = fmaf(3.f, hA_m, hA_u);
  float oEO = fmaf(3.f, hB_m, hB_u);
  float oOE = fmaf(3.f, hA_m, hA_d);
  float oOO = fmaf(3.f, hB_m, hB_d);

  float* op = out + (size_t)bo * (HO * WO) + (u32)(2 * m) * WO + 2 * n;
  op[0] = fmaf(oEE, 0.0625f, bv);
  if (rt) op[1] = fmaf(oEO, 0.0625f, bv);
  if (dn) {
    op[WO] = fmaf(oOE, 0.0625f, bv);
    if (rt) op[WO + 1] = fmaf(oOO, 0.0625f, bv);
  }
}

// Slow but correct fallback if ws_size is insufficient (no workspace needed).
__global__ __launch_bounds__(256) void fallback_kernel(
    const float* __restrict__ x, const float* __restrict__ w,
    const float* __restrict__ bias, float* __restrict__ out) {
  u32 idx = blockIdx.x * 256u + threadIdx.x;
  const u32 total = (u32)B_ * COUT * HO * WO;
  if (idx >= total) return;
  u32 j = idx % WO;
  u32 r1 = idx / WO;
  u32 i = r1 % HO;
  u32 bo = r1 / HO;
  int o = (int)(bo & 511u);
  int b = (int)(bo >> 9);
  int m = (int)(i >> 1), n = (int)(j >> 1);
  int ie = !(i & 1), je = !(j & 1);
  int rA = ie ? m - 1 : m;
  int cA = je ? n - 1 : n;
  float w_r0 = ie ? 1.f : 3.f, w_r1 = ie ? 3.f : 1.f;
  float w_c0 = je ? 1.f : 3.f, w_c1 = je ? 3.f : 1.f;
  const float* xb = x + (size_t)b * CIN * S_;
  float acc = 0.f;
  for (int c = 0; c < CIN; ++c) {
    const float* xc = xb + (size_t)c * S_;
    float y = 0.f;
    if (rA >= 0) {
      if (cA >= 0) y += w_r0 * w_c0 * xc[rA * 64 + cA];
      y += w_r0 * w_c1 * xc[rA * 64 + cA + 1];
    }
    if (cA >= 0) y += w_r1 * w_c0 * xc[(rA + 1) * 64 + cA];
    y += w_r1 * w_c1 * xc[(rA + 1) * 64 + cA + 1];
    acc += y * w[(size_t)o * CIN + c];
  }
  out[idx] = acc * 0.0625f + bias[o];
}

extern "C" void kernel_launch(void* const* d_in, const int* in_sizes, int n_in,
                              void* d_out, int out_size, void* d_ws,
                              size_t ws_size, hipStream_t stream) {
  const float* x = (const float*)d_in[0];
  // d_in[1] = fir_kernel (deterministic, hard-coded taps above)
  const float* w = (const float*)d_in[2];
  const float* bias = (const float*)d_in[3];
  float* out = (float*)d_out;

  const size_t xt_bytes = (size_t)B_ * S_ * CIN * 2;       // 64 MiB
  const size_t wt_off = xt_bytes;
  const size_t wt_bytes = (size_t)COUT * CIN * 2;          // 512 KiB
  const size_t z_off = wt_off + ((wt_bytes + 255) & ~(size_t)255);
  const size_t need = z_off + (size_t)B_ * COUT * S_ * 2;  // ~128.5 MiB
  const size_t total_out = (size_t)B_ * COUT * HO * WO;
  const u32 nblk_out = (u32)((total_out + 255) / 256);

  if (ws_size >= need) {
    u16* xt = (u16*)d_ws;
    u16* wt = (u16*)((char*)d_ws + wt_off);
    u16* zz = (u16*)((char*)d_ws + z_off);
    conv_w_kernel<<<128, 256, 0, stream>>>(w, wt);
    conv_x_kernel<<<dim3(32, 16, B_), 256, 0, stream>>>(x, xt);
    gemm_kernel<<<dim3(32, 4, B_), 256, 0, stream>>>(wt, xt, zz);
    const u32 nblk_up = (u32)(((size_t)B_ * COUT * S_) / 256);  // 131072
    upsample_kernel<<<nblk_up, 256, 0, stream>>>(zz, bias, out);
  } else {
    fallback_kernel<<<nblk_out, 256, 0, stream>>>(x, w, bias, out);
  }
}

// Round 3
// 336.149 us; speedup vs baseline: 1.5493x; 1.0456x over previous
//
#include <hip/hip_runtime.h>

// ---------------------------------------------------------------------------
// UpsampleLayer: out = Upsample2x_FIR( W @ x ) + bias   (upsample and 1x1 conv
// commute, so the GEMM runs at 64x64 instead of 127x127 -> 4x fewer FLOPs).
//
// Shapes: x[16][512][64][64] f32, w[512][512] f32, bias[512] f32 (zeros),
//         out[16][512][127][127] f32.
// Upsample (derived from lax.conv_general_dilated, lhs_dilation=2, pad=(2,1),
// kernel outer([1,3,3,1],[1,3,3,1])/16):
//   y[2m]   = (3*z[m] + z[m-1]) / 4      (z[-1] = 0)
//   y[2m+1] = (3*z[m] + z[m+1]) / 4
// per axis; output spatial size = 127.
// R1: one thread -> 2x2 quad (436 -> ~266 us; still latency/sector-bound).
// R2: one block per (b,o) image; z staged in LDS via u16x8; lane = output
// column -> perfectly contiguous stores; taps are per-lane constants.
// ---------------------------------------------------------------------------

#define B_   16
#define CIN  512
#define COUT 512
#define S_   4096   // 64*64
#define HO   127
#define WO   127

typedef unsigned int  u32;
typedef unsigned short u16;
typedef __attribute__((ext_vector_type(8))) short  bf16x8;
typedef __attribute__((ext_vector_type(8))) u16    u16x8;
typedef __attribute__((ext_vector_type(4))) float  f32x4;

static __device__ __forceinline__ u16 f2bf(float f) {
  u32 u = __float_as_uint(f);
  u += 0x7FFFu + ((u >> 16) & 1u);   // round-to-nearest-even (inputs finite)
  return (u16)(u >> 16);
}
static __device__ __forceinline__ float bf2f(u16 h) {
  return __uint_as_float(((u32)h) << 16);
}

#if defined(__has_builtin)
#if __has_builtin(__builtin_amdgcn_global_load_lds)
#define HAS_GLOAD 1
#endif
#endif
#ifndef HAS_GLOAD
#define HAS_GLOAD 0
#endif

#if HAS_GLOAD
static __device__ __forceinline__ void gload16(const char* g, char* l) {
  __builtin_amdgcn_global_load_lds(
      (const __attribute__((address_space(1))) unsigned int*)g,
      (__attribute__((address_space(3))) unsigned int*)l, 16, 0, 0);
}
#endif

// ---------------------------------------------------------------------------
// Tiled operand layout (both W and X^T), per 128(row) x 32(k) tile = 8 KiB:
//   tile = 512 units of 16B; unit u = kg*128 + r  (kg = (k%32)/8, r = row%128)
//   unit contents = 8 bf16, k = k0 + kg*8 + e.
// ---------------------------------------------------------------------------

// w[o][c] f32 -> wt tiled bf16. 32768 units total.
__global__ __launch_bounds__(256) void conv_w_kernel(
    const float* __restrict__ w, u16* __restrict__ wt) {
  int g = blockIdx.x * 256 + threadIdx.x;  // unit index
  int t_idx = g >> 9;                      // tile index (to*16 + tk)
  int u = g & 511;
  int to = t_idx >> 4, tk = t_idx & 15;
  int r = u & 127, kg = u >> 7;
  int o = to * 128 + r;
  int c = tk * 32 + kg * 8;
  const float4* src = reinterpret_cast<const float4*>(w + (size_t)o * CIN + c);
  float4 lo = src[0], hi = src[1];
  u16x8 pk;
  pk[0] = f2bf(lo.x); pk[1] = f2bf(lo.y); pk[2] = f2bf(lo.z); pk[3] = f2bf(lo.w);
  pk[4] = f2bf(hi.x); pk[5] = f2bf(hi.y); pk[6] = f2bf(hi.z); pk[7] = f2bf(hi.w);
  *reinterpret_cast<u16x8*>(wt + (size_t)g * 8) = pk;
}

// x[b][c][s] f32 -> xt tiled bf16 with (s,c) transpose.
// block = (ts, tk, b): 128 s-cols x 32 c-rows.
__global__ __launch_bounds__(256) void conv_x_kernel(
    const float* __restrict__ x, u16* __restrict__ xt) {
  int ts = blockIdx.x, tk = blockIdx.y, b = blockIdx.z;
  int t = threadIdx.x;
  __shared__ float lf[32 * 128];
  const float* src = x + ((size_t)(b * CIN + tk * 32)) * S_ + ts * 128;
#pragma unroll
  for (int i = 0; i < 4; ++i) {  // 1024 float4 total
    int q = i * 256 + t;
    int c = q >> 5, sq = q & 31;
    *reinterpret_cast<float4*>(&lf[c * 128 + sq * 4]) =
        *reinterpret_cast<const float4*>(src + (size_t)c * S_ + sq * 4);
  }
  __syncthreads();
  size_t tile_base = (((size_t)(b * 32 + ts)) * 16 + tk) * 512;  // in units
#pragma unroll
  for (int i = 0; i < 2; ++i) {
    int u = i * 256 + t;
    int kg = u >> 7, r = u & 127;
    u16x8 pk;
#pragma unroll
    for (int e = 0; e < 8; ++e) pk[e] = f2bf(lf[(kg * 8 + e) * 128 + r]);
    *reinterpret_cast<u16x8*>(xt + (tile_base + u) * 8) = pk;
  }
}

// GEMM: Z[b][o][s] = sum_c W[o][c] * X[b][c][s], 128x128 tile, BK=32,
// 4 waves (2x2), each wave 64x64 = 4x4 frags of mfma_f32_16x16x32_bf16.
__global__ __launch_bounds__(256) void gemm_kernel(
    const u16* __restrict__ wt, const u16* __restrict__ xt,
    u16* __restrict__ z) {
  int nt = blockIdx.x, mt = blockIdx.y, b = blockIdx.z;
  int t = threadIdx.x;
  __shared__ short lds[8192];  // A: bytes [0,8192), B: bytes [8192,16384)
  char* lA = (char*)&lds[0];
  char* lB = lA + 8192;

  int lane = t & 63, wid = t >> 6;
  int wr = wid >> 1, wc = wid & 1;
  int lr = lane & 15, kg = lane >> 4;

  f32x4 acc[4][4];
#pragma unroll
  for (int m = 0; m < 4; ++m)
#pragma unroll
    for (int n = 0; n < 4; ++n) acc[m][n] = f32x4{0.f, 0.f, 0.f, 0.f};

  const char* gA = (const char*)wt + (size_t)(mt * 16) * 8192;
  const char* gB = (const char*)xt + ((size_t)(b * 32 + nt)) * 16 * 8192;

  int abyte[4], bbyte[4];
#pragma unroll
  for (int m = 0; m < 4; ++m) abyte[m] = (kg * 128 + wr * 64 + m * 16 + lr) * 16;
#pragma unroll
  for (int n = 0; n < 4; ++n) bbyte[n] = (kg * 128 + wc * 64 + n * 16 + lr) * 16;

  for (int ks = 0; ks < 16; ++ks) {
    const char* pA = gA + (size_t)ks * 8192;
    const char* pB = gB + (size_t)ks * 8192;
#if HAS_GLOAD
    __syncthreads();  // previous compute done reading LDS
    gload16(pA + t * 16, lA + t * 16);
    gload16(pA + 4096 + t * 16, lA + 4096 + t * 16);
    gload16(pB + t * 16, lB + t * 16);
    gload16(pB + 4096 + t * 16, lB + 4096 + t * 16);
    __syncthreads();  // drains vmcnt, publishes LDS
#else
    u16x8 va0 = *reinterpret_cast<const u16x8*>(pA + t * 16);
    u16x8 va1 = *reinterpret_cast<const u16x8*>(pA + 4096 + t * 16);
    u16x8 vb0 = *reinterpret_cast<const u16x8*>(pB + t * 16);
    u16x8 vb1 = *reinterpret_cast<const u16x8*>(pB + 4096 + t * 16);
    __syncthreads();
    *reinterpret_cast<u16x8*>(lA + t * 16) = va0;
    *reinterpret_cast<u16x8*>(lA + 4096 + t * 16) = va1;
    *reinterpret_cast<u16x8*>(lB + t * 16) = vb0;
    *reinterpret_cast<u16x8*>(lB + 4096 + t * 16) = vb1;
    __syncthreads();
#endif
    bf16x8 av[4], bv[4];
#pragma unroll
    for (int m = 0; m < 4; ++m)
      av[m] = *reinterpret_cast<const bf16x8*>(lA + abyte[m]);
#pragma unroll
    for (int n = 0; n < 4; ++n)
      bv[n] = *reinterpret_cast<const bf16x8*>(lB + bbyte[n]);
#pragma unroll
    for (int m = 0; m < 4; ++m)
#pragma unroll
      for (int n = 0; n < 4; ++n)
        acc[m][n] = __builtin_amdgcn_mfma_f32_16x16x32_bf16(
            av[m], bv[n], acc[m][n], 0, 0, 0);
  }

  // C/D layout: col = lane&15 (s), row = (lane>>4)*4 + reg (o).
  int o_b = mt * 128 + wr * 64 + kg * 4;
  int s_b = nt * 128 + wc * 64 + lr;
#pragma unroll
  for (int m = 0; m < 4; ++m)
#pragma unroll
    for (int n = 0; n < 4; ++n) {
      f32x4 v = acc[m][n];
      size_t base = ((size_t)(b * COUT + o_b + m * 16)) * S_ + (s_b + n * 16);
#pragma unroll
      for (int r = 0; r < 4; ++r) z[base + (size_t)r * S_] = f2bf(v[r]);
    }
}

// R2 upsample: one block per (b,o) image. z image (8 KB) staged in LDS with
// u16x8 loads; 4 row-groups x 64 lanes; lane == output column -> contiguous
// 4B-per-lane stores. Output row r draws on z rows ra=(r-1)>>1, rb=ra+1 with
// taps (1,3) for even r, (3,1) for odd r; same per column.
__global__ __launch_bounds__(256) void upsample_kernel(
    const u16* __restrict__ z, const float* __restrict__ bias,
    float* __restrict__ out) {
  int bo = blockIdx.x;  // b*512 + o
  int t = threadIdx.x;
  __shared__ u16 zl[64 * 64];
  {
    u16x8* dst = reinterpret_cast<u16x8*>(zl);
    const u16x8* src = reinterpret_cast<const u16x8*>(z + ((size_t)bo << 12));
    dst[t] = src[t];
    dst[t + 256] = src[t + 256];
  }
  float bv = bias[bo & 511];
  __syncthreads();

  int lane = t & 63;
  int rg = t >> 6;  // 0..3; row parity = rg&1 (rows rg, rg+4, ...)
  float* ob = out + (size_t)bo * (HO * WO);

  // column constants for the two columns this lane owns: j0 = lane, j1 = lane+64
  int j0 = lane, j1 = lane + 64;
  int ca0 = (j0 - 1) >> 1, ca1 = (j1 - 1) >> 1;  // left z col (may be -1)
  // col taps: even j -> (1,3); odd j -> (3,1); left tap 0 at j==0
  float c0a = (j0 & 1) ? 3.f : ((j0 == 0) ? 0.f : 1.f);
  float c0b = (j0 & 1) ? 1.f : 3.f;
  float c1a = (j1 & 1) ? 3.f : 1.f;
  float c1b = (j1 & 1) ? 1.f : 3.f;
  int ca0n = (ca0 < 0) ? 0 : ca0;
  int cb0 = ca0 + 1, cb1 = ca1 + 1;
  bool has_j1 = (lane < 63);  // j1 <= 126
  // row taps: even r -> (1,3); odd r -> (3,1)
  float wa_base = (rg & 1) ? 3.f : 1.f;
  float wb = (rg & 1) ? 1.f : 3.f;

  for (int r = rg; r < HO; r += 4) {
    int ra = (r - 1) >> 1;  // -1 at r==0
    int rb = ra + 1;
    float wa = (ra < 0) ? 0.f : wa_base;
    int ran = (ra < 0) ? 0 : ra;
    const u16* rowA = zl + (ran << 6);
    const u16* rowB = zl + (rb << 6);
    // column j0
    float hA0 = c0a * bf2f(rowA[ca0n]) + c0b * bf2f(rowA[cb0]);
    float hB0 = c0a * bf2f(rowB[ca0n]) + c0b * bf2f(rowB[cb0]);
    float v0 = wa * hA0 + wb * hB0;
    float* orow = ob + r * WO;
    orow[j0] = fmaf(v0, 0.0625f, bv);
    // column j1
    if (has_j1) {
      float hA1 = c1a * bf2f(rowA[ca1]) + c1b * bf2f(rowA[cb1]);
      float hB1 = c1a * bf2f(rowB[ca1]) + c1b * bf2f(rowB[cb1]);
      float v1 = wa * hA1 + wb * hB1;
      orow[j1] = fmaf(v1, 0.0625f, bv);
    }
  }
}

// Slow but correct fallback if ws_size is insufficient (no workspace needed).
__global__ __launch_bounds__(256) void fallback_kernel(
    const float* __restrict__ x, const float* __restrict__ w,
    const float* __restrict__ bias, float* __restrict__ out) {
  u32 idx = blockIdx.x * 256u + threadIdx.x;
  const u32 total = (u32)B_ * COUT * HO * WO;
  if (idx >= total) return;
  u32 j = idx % WO;
  u32 r1 = idx / WO;
  u32 i = r1 % HO;
  u32 bo = r1 / HO;
  int o = (int)(bo & 511u);
  int b = (int)(bo >> 9);
  int m = (int)(i >> 1), n = (int)(j >> 1);
  int ie = !(i & 1), je = !(j & 1);
  int rA = ie ? m - 1 : m;
  int cA = je ? n - 1 : n;
  float w_r0 = ie ? 1.f : 3.f, w_r1 = ie ? 3.f : 1.f;
  float w_c0 = je ? 1.f : 3.f, w_c1 = je ? 3.f : 1.f;
  const float* xb = x + (size_t)b * CIN * S_;
  float acc = 0.f;
  for (int c = 0; c < CIN; ++c) {
    const float* xc = xb + (size_t)c * S_;
    float y = 0.f;
    if (rA >= 0) {
      if (cA >= 0) y += w_r0 * w_c0 * xc[rA * 64 + cA];
      y += w_r0 * w_c1 * xc[rA * 64 + cA + 1];
    }
    if (cA >= 0) y += w_r1 * w_c0 * xc[(rA + 1) * 64 + cA];
    y += w_r1 * w_c1 * xc[(rA + 1) * 64 + cA + 1];
    acc += y * w[(size_t)o * CIN + c];
  }
  out[idx] = acc * 0.0625f + bias[o];
}

extern "C" void kernel_launch(void* const* d_in, const int* in_sizes, int n_in,
                              void* d_out, int out_size, void* d_ws,
                              size_t ws_size, hipStream_t stream) {
  const float* x = (const float*)d_in[0];
  // d_in[1] = fir_kernel (deterministic, hard-coded taps above)
  const float* w = (const float*)d_in[2];
  const float* bias = (const float*)d_in[3];
  float* out = (float*)d_out;

  const size_t xt_bytes = (size_t)B_ * S_ * CIN * 2;       // 64 MiB
  const size_t wt_off = xt_bytes;
  const size_t wt_bytes = (size_t)COUT * CIN * 2;          // 512 KiB
  const size_t z_off = wt_off + ((wt_bytes + 255) & ~(size_t)255);
  const size_t need = z_off + (size_t)B_ * COUT * S_ * 2;  // ~128.5 MiB
  const size_t total_out = (size_t)B_ * COUT * HO * WO;
  const u32 nblk_out = (u32)((total_out + 255) / 256);

  if (ws_size >= need) {
    u16* xt = (u16*)d_ws;
    u16* wt = (u16*)((char*)d_ws + wt_off);
    u16* zz = (u16*)((char*)d_ws + z_off);
    conv_w_kernel<<<128, 256, 0, stream>>>(w, wt);
    conv_x_kernel<<<dim3(32, 16, B_), 256, 0, stream>>>(x, xt);
    gemm_kernel<<<dim3(32, 4, B_), 256, 0, stream>>>(wt, xt, zz);
    upsample_kernel<<<B_ * COUT, 256, 0, stream>>>(zz, bias, out);
  } else {
    fallback_kernel<<<nblk_out, 256, 0, stream>>>(x, w, bias, out);
  }
}

// Round 4
// 281.468 us; speedup vs baseline: 1.8503x; 1.1943x over previous
//
#include <hip/hip_runtime.h>

// ---------------------------------------------------------------------------
// UpsampleLayer: out = Upsample2x_FIR( W @ x ) + bias   (upsample and 1x1 conv
// commute, so the GEMM runs at 64x64 instead of 127x127 -> 4x fewer FLOPs).
//
// Shapes: x[16][512][64][64] f32, w[512][512] f32, bias[512] f32 (zeros),
//         out[16][512][127][127] f32.
// Upsample (derived from lax.conv_general_dilated, lhs_dilation=2, pad=(2,1),
// kernel outer([1,3,3,1],[1,3,3,1])/16):
//   y[2m]   = (3*z[m] + z[m-1]) / 4      (z[-1] = 0)
//   y[2m+1] = (3*z[m] + z[m+1]) / 4
// per axis; output spatial size = 127.
// R1: one thread -> 2x2 quad (436 -> ~266 us; latency/sector-bound).
// R2: LDS-staged image (only ~-15 us total: 8 scalar ds_read_u16 per row made
//     it LDS-pipe-bound, ~79 us/CU of DS serialization).
// R3: no LDS at all. One wave per image, lane = z column, march rows keeping
//     previous row's horizontal FIR in registers; horizontal neighbors via
//     +-2B global loads (L2/L3-resident). Pure coalesced dword stores.
// ---------------------------------------------------------------------------

#define B_   16
#define CIN  512
#define COUT 512
#define S_   4096   // 64*64
#define HO   127
#define WO   127

typedef unsigned int  u32;
typedef unsigned short u16;
typedef __attribute__((ext_vector_type(8))) short  bf16x8;
typedef __attribute__((ext_vector_type(8))) u16    u16x8;
typedef __attribute__((ext_vector_type(4))) float  f32x4;

static __device__ __forceinline__ u16 f2bf(float f) {
  u32 u = __float_as_uint(f);
  u += 0x7FFFu + ((u >> 16) & 1u);   // round-to-nearest-even (inputs finite)
  return (u16)(u >> 16);
}
static __device__ __forceinline__ float bf2f(u16 h) {
  return __uint_as_float(((u32)h) << 16);
}

#if defined(__has_builtin)
#if __has_builtin(__builtin_amdgcn_global_load_lds)
#define HAS_GLOAD 1
#endif
#endif
#ifndef HAS_GLOAD
#define HAS_GLOAD 0
#endif

#if HAS_GLOAD
static __device__ __forceinline__ void gload16(const char* g, char* l) {
  __builtin_amdgcn_global_load_lds(
      (const __attribute__((address_space(1))) unsigned int*)g,
      (__attribute__((address_space(3))) unsigned int*)l, 16, 0, 0);
}
#endif

// ---------------------------------------------------------------------------
// Tiled operand layout (both W and X^T), per 128(row) x 32(k) tile = 8 KiB:
//   tile = 512 units of 16B; unit u = kg*128 + r  (kg = (k%32)/8, r = row%128)
//   unit contents = 8 bf16, k = k0 + kg*8 + e.
// ---------------------------------------------------------------------------

// w[o][c] f32 -> wt tiled bf16. 32768 units total.
__global__ __launch_bounds__(256) void conv_w_kernel(
    const float* __restrict__ w, u16* __restrict__ wt) {
  int g = blockIdx.x * 256 + threadIdx.x;  // unit index
  int t_idx = g >> 9;                      // tile index (to*16 + tk)
  int u = g & 511;
  int to = t_idx >> 4, tk = t_idx & 15;
  int r = u & 127, kg = u >> 7;
  int o = to * 128 + r;
  int c = tk * 32 + kg * 8;
  const float4* src = reinterpret_cast<const float4*>(w + (size_t)o * CIN + c);
  float4 lo = src[0], hi = src[1];
  u16x8 pk;
  pk[0] = f2bf(lo.x); pk[1] = f2bf(lo.y); pk[2] = f2bf(lo.z); pk[3] = f2bf(lo.w);
  pk[4] = f2bf(hi.x); pk[5] = f2bf(hi.y); pk[6] = f2bf(hi.z); pk[7] = f2bf(hi.w);
  *reinterpret_cast<u16x8*>(wt + (size_t)g * 8) = pk;
}

// x[b][c][s] f32 -> xt tiled bf16 with (s,c) transpose.
// block = (ts, tk, b): 128 s-cols x 32 c-rows.
__global__ __launch_bounds__(256) void conv_x_kernel(
    const float* __restrict__ x, u16* __restrict__ xt) {
  int ts = blockIdx.x, tk = blockIdx.y, b = blockIdx.z;
  int t = threadIdx.x;
  __shared__ float lf[32 * 128];
  const float* src = x + ((size_t)(b * CIN + tk * 32)) * S_ + ts * 128;
#pragma unroll
  for (int i = 0; i < 4; ++i) {  // 1024 float4 total
    int q = i * 256 + t;
    int c = q >> 5, sq = q & 31;
    *reinterpret_cast<float4*>(&lf[c * 128 + sq * 4]) =
        *reinterpret_cast<const float4*>(src + (size_t)c * S_ + sq * 4);
  }
  __syncthreads();
  size_t tile_base = (((size_t)(b * 32 + ts)) * 16 + tk) * 512;  // in units
#pragma unroll
  for (int i = 0; i < 2; ++i) {
    int u = i * 256 + t;
    int kg = u >> 7, r = u & 127;
    u16x8 pk;
#pragma unroll
    for (int e = 0; e < 8; ++e) pk[e] = f2bf(lf[(kg * 8 + e) * 128 + r]);
    *reinterpret_cast<u16x8*>(xt + (tile_base + u) * 8) = pk;
  }
}

// GEMM: Z[b][o][s] = sum_c W[o][c] * X[b][c][s], 128x128 tile, BK=32,
// 4 waves (2x2), each wave 64x64 = 4x4 frags of mfma_f32_16x16x32_bf16.
__global__ __launch_bounds__(256) void gemm_kernel(
    const u16* __restrict__ wt, const u16* __restrict__ xt,
    u16* __restrict__ z) {
  int nt = blockIdx.x, mt = blockIdx.y, b = blockIdx.z;
  int t = threadIdx.x;
  __shared__ short lds[8192];  // A: bytes [0,8192), B: bytes [8192,16384)
  char* lA = (char*)&lds[0];
  char* lB = lA + 8192;

  int lane = t & 63, wid = t >> 6;
  int wr = wid >> 1, wc = wid & 1;
  int lr = lane & 15, kg = lane >> 4;

  f32x4 acc[4][4];
#pragma unroll
  for (int m = 0; m < 4; ++m)
#pragma unroll
    for (int n = 0; n < 4; ++n) acc[m][n] = f32x4{0.f, 0.f, 0.f, 0.f};

  const char* gA = (const char*)wt + (size_t)(mt * 16) * 8192;
  const char* gB = (const char*)xt + ((size_t)(b * 32 + nt)) * 16 * 8192;

  int abyte[4], bbyte[4];
#pragma unroll
  for (int m = 0; m < 4; ++m) abyte[m] = (kg * 128 + wr * 64 + m * 16 + lr) * 16;
#pragma unroll
  for (int n = 0; n < 4; ++n) bbyte[n] = (kg * 128 + wc * 64 + n * 16 + lr) * 16;

  for (int ks = 0; ks < 16; ++ks) {
    const char* pA = gA + (size_t)ks * 8192;
    const char* pB = gB + (size_t)ks * 8192;
#if HAS_GLOAD
    __syncthreads();  // previous compute done reading LDS
    gload16(pA + t * 16, lA + t * 16);
    gload16(pA + 4096 + t * 16, lA + 4096 + t * 16);
    gload16(pB + t * 16, lB + t * 16);
    gload16(pB + 4096 + t * 16, lB + 4096 + t * 16);
    __syncthreads();  // drains vmcnt, publishes LDS
#else
    u16x8 va0 = *reinterpret_cast<const u16x8*>(pA + t * 16);
    u16x8 va1 = *reinterpret_cast<const u16x8*>(pA + 4096 + t * 16);
    u16x8 vb0 = *reinterpret_cast<const u16x8*>(pB + t * 16);
    u16x8 vb1 = *reinterpret_cast<const u16x8*>(pB + 4096 + t * 16);
    __syncthreads();
    *reinterpret_cast<u16x8*>(lA + t * 16) = va0;
    *reinterpret_cast<u16x8*>(lA + 4096 + t * 16) = va1;
    *reinterpret_cast<u16x8*>(lB + t * 16) = vb0;
    *reinterpret_cast<u16x8*>(lB + 4096 + t * 16) = vb1;
    __syncthreads();
#endif
    bf16x8 av[4], bv[4];
#pragma unroll
    for (int m = 0; m < 4; ++m)
      av[m] = *reinterpret_cast<const bf16x8*>(lA + abyte[m]);
#pragma unroll
    for (int n = 0; n < 4; ++n)
      bv[n] = *reinterpret_cast<const bf16x8*>(lB + bbyte[n]);
#pragma unroll
    for (int m = 0; m < 4; ++m)
#pragma unroll
      for (int n = 0; n < 4; ++n)
        acc[m][n] = __builtin_amdgcn_mfma_f32_16x16x32_bf16(
            av[m], bv[n], acc[m][n], 0, 0, 0);
  }

  // C/D layout: col = lane&15 (s), row = (lane>>4)*4 + reg (o).
  int o_b = mt * 128 + wr * 64 + kg * 4;
  int s_b = nt * 128 + wc * 64 + lr;
#pragma unroll
  for (int m = 0; m < 4; ++m)
#pragma unroll
    for (int n = 0; n < 4; ++n) {
      f32x4 v = acc[m][n];
      size_t base = ((size_t)(b * COUT + o_b + m * 16)) * S_ + (s_b + n * 16);
#pragma unroll
      for (int r = 0; r < 4; ++r) z[base + (size_t)r * S_] = f2bf(v[r]);
    }
}

// R3 upsample: one wave per (b,o) image, lane = z column n (owns output cols
// 2n and 2n+1). March m = 0..63 down the image:
//   h[m] pair: hA(col 2n) = 1*z[m][n-1] + 3*z[m][n]   (tap 0 at n==0)
//              hB(col 2n+1) = 3*z[m][n] + 1*z[m][n+1]
//   emit row 2m-1 = 3*h[m-1] + h[m]  (m>0)
//   emit row 2m   = 1*h[m-1] + 3*h[m]   (h[-1] = 0)
// Neighbors via +-2B coalesced global loads (z is L2/L3-resident; edge
// garbage is multiplied by 0). No LDS, no shuffles; stores are contiguous
// dwords. 4 waves (4 images) per block.
__global__ __launch_bounds__(256) void upsample_kernel(
    const u16* __restrict__ z, const float* __restrict__ bias,
    float* __restrict__ out) {
  int t = threadIdx.x;
  int lane = t & 63;
  int bo = blockIdx.x * 4 + (t >> 6);  // b*512 + o
  const u16* zp = z + ((size_t)bo << 12) + lane;
  float bv = bias[bo & 511];
  float* ob = out + (size_t)bo * (HO * WO) + 2 * lane;

  float wl = (lane == 0) ? 0.f : 1.f;   // left-tap mask
  bool has_j1 = (lane < 63);            // col 2n+1 <= 125 valid

  // prefetch row 0
  u16 c_ = zp[0], l_ = zp[-1], r_ = zp[1];
  float hA_p = 0.f, hB_p = 0.f;

  for (int m = 0; m < 64; ++m) {
    float zc = bf2f(c_), zl = bf2f(l_) * wl, zr = bf2f(r_);
    if (m < 63) {  // prefetch next row
      const u16* q = zp + 64;
      c_ = q[0]; l_ = q[-1]; r_ = q[1];
      zp = q;
    }
    float hA = fmaf(3.f, zc, zl);
    float hB = fmaf(3.f, zc, zr);

    float* p_even = ob + (u32)(2 * m) * WO;
    if (m > 0) {  // row 2m-1 = 3*h_prev + h
      float* p_odd = p_even - WO;
      p_odd[0] = fmaf(fmaf(3.f, hA_p, hA), 0.0625f, bv);
      if (has_j1) p_odd[1] = fmaf(fmaf(3.f, hB_p, hB), 0.0625f, bv);
    }
    // row 2m = h_prev + 3*h
    p_even[0] = fmaf(fmaf(3.f, hA, hA_p), 0.0625f, bv);
    if (has_j1) p_even[1] = fmaf(fmaf(3.f, hB, hB_p), 0.0625f, bv);

    hA_p = hA; hB_p = hB;
  }
}

// Slow but correct fallback if ws_size is insufficient (no workspace needed).
__global__ __launch_bounds__(256) void fallback_kernel(
    const float* __restrict__ x, const float* __restrict__ w,
    const float* __restrict__ bias, float* __restrict__ out) {
  u32 idx = blockIdx.x * 256u + threadIdx.x;
  const u32 total = (u32)B_ * COUT * HO * WO;
  if (idx >= total) return;
  u32 j = idx % WO;
  u32 r1 = idx / WO;
  u32 i = r1 % HO;
  u32 bo = r1 / HO;
  int o = (int)(bo & 511u);
  int b = (int)(bo >> 9);
  int m = (int)(i >> 1), n = (int)(j >> 1);
  int ie = !(i & 1), je = !(j & 1);
  int rA = ie ? m - 1 : m;
  int cA = je ? n - 1 : n;
  float w_r0 = ie ? 1.f : 3.f, w_r1 = ie ? 3.f : 1.f;
  float w_c0 = je ? 1.f : 3.f, w_c1 = je ? 3.f : 1.f;
  const float* xb = x + (size_t)b * CIN * S_;
  float acc = 0.f;
  for (int c = 0; c < CIN; ++c) {
    const float* xc = xb + (size_t)c * S_;
    float y = 0.f;
    if (rA >= 0) {
      if (cA >= 0) y += w_r0 * w_c0 * xc[rA * 64 + cA];
      y += w_r0 * w_c1 * xc[rA * 64 + cA + 1];
    }
    if (cA >= 0) y += w_r1 * w_c0 * xc[(rA + 1) * 64 + cA];
    y += w_r1 * w_c1 * xc[(rA + 1) * 64 + cA + 1];
    acc += y * w[(size_t)o * CIN + c];
  }
  out[idx] = acc * 0.0625f + bias[o];
}

extern "C" void kernel_launch(void* const* d_in, const int* in_sizes, int n_in,
                              void* d_out, int out_size, void* d_ws,
                              size_t ws_size, hipStream_t stream) {
  const float* x = (const float*)d_in[0];
  // d_in[1] = fir_kernel (deterministic, hard-coded taps above)
  const float* w = (const float*)d_in[2];
  const float* bias = (const float*)d_in[3];
  float* out = (float*)d_out;

  const size_t xt_bytes = (size_t)B_ * S_ * CIN * 2;       // 64 MiB
  const size_t wt_off = xt_bytes;
  const size_t wt_bytes = (size_t)COUT * CIN * 2;          // 512 KiB
  const size_t z_off = wt_off + ((wt_bytes + 255) & ~(size_t)255);
  const size_t need = z_off + (size_t)B_ * COUT * S_ * 2;  // ~128.5 MiB
  const size_t total_out = (size_t)B_ * COUT * HO * WO;
  const u32 nblk_out = (u32)((total_out + 255) / 256);

  if (ws_size >= need) {
    u16* xt = (u16*)d_ws;
    u16* wt = (u16*)((char*)d_ws + wt_off);
    u16* zz = (u16*)((char*)d_ws + z_off);
    conv_w_kernel<<<128, 256, 0, stream>>>(w, wt);
    conv_x_kernel<<<dim3(32, 16, B_), 256, 0, stream>>>(x, xt);
    gemm_kernel<<<dim3(32, 4, B_), 256, 0, stream>>>(wt, xt, zz);
    upsample_kernel<<<(B_ * COUT) / 4, 256, 0, stream>>>(zz, bias, out);
  } else {
    fallback_kernel<<<nblk_out, 256, 0, stream>>>(x, w, bias, out);
  }
}

// Round 5
// 262.844 us; speedup vs baseline: 1.9814x; 1.0709x over previous
//
#include <hip/hip_runtime.h>

// ---------------------------------------------------------------------------
// UpsampleLayer: out = Upsample2x_FIR( W @ x ) + bias   (upsample and 1x1 conv
// commute, so the GEMM runs at 64x64 instead of 127x127 -> 4x fewer FLOPs).
//
// Shapes: x[16][512][64][64] f32, w[512][512] f32, bias[512] f32 (zeros),
//         out[16][512][127][127] f32.
// Upsample (derived from lax.conv_general_dilated, lhs_dilation=2, pad=(2,1),
// kernel outer([1,3,3,1],[1,3,3,1])/16):
//   y[2m]   = (3*z[m] + z[m-1]) / 4      (z[-1] = 0)
//   y[2m+1] = (3*z[m] + z[m+1]) / 4
// per axis; output spatial size = 127.
// R1: one thread -> 2x2 quad (436 -> ~266 us; latency/sector-bound).
// R2: LDS-staged image (-15 us: LDS-pipe-bound, 8 ds_read_u16/row).
// R3: register row-march, no LDS (196 us; stores half-dense -> 2x sector
//     transactions = ~150 us of write time).
// R4: dwordx2 per-lane stores (dense 512B wave-spans, halves sector count);
//     2 waves per image (halo h-row) for 2x TLP on the z-load latency.
// ---------------------------------------------------------------------------

#define B_   16
#define CIN  512
#define COUT 512
#define S_   4096   // 64*64
#define HO   127
#define WO   127

typedef unsigned int  u32;
typedef unsigned short u16;
typedef __attribute__((ext_vector_type(8))) short  bf16x8;
typedef __attribute__((ext_vector_type(8))) u16    u16x8;
typedef __attribute__((ext_vector_type(4))) float  f32x4;
typedef __attribute__((ext_vector_type(2))) float  f32x2;

static __device__ __forceinline__ u16 f2bf(float f) {
  u32 u = __float_as_uint(f);
  u += 0x7FFFu + ((u >> 16) & 1u);   // round-to-nearest-even (inputs finite)
  return (u16)(u >> 16);
}
static __device__ __forceinline__ float bf2f(u16 h) {
  return __uint_as_float(((u32)h) << 16);
}
// 8B store at 4B-guaranteed alignment (gfx950 global dwordx2 needs only
// dword alignment; clang emits global_store_dwordx2 for align-4 <2 x float>).
static __device__ __forceinline__ void store2(float* p, float a, float b) {
  f32x2 v; v.x = a; v.y = b;
  __builtin_memcpy(p, &v, 8);
}

#if defined(__has_builtin)
#if __has_builtin(__builtin_amdgcn_global_load_lds)
#define HAS_GLOAD 1
#endif
#endif
#ifndef HAS_GLOAD
#define HAS_GLOAD 0
#endif

#if HAS_GLOAD
static __device__ __forceinline__ void gload16(const char* g, char* l) {
  __builtin_amdgcn_global_load_lds(
      (const __attribute__((address_space(1))) unsigned int*)g,
      (__attribute__((address_space(3))) unsigned int*)l, 16, 0, 0);
}
#endif

// ---------------------------------------------------------------------------
// Tiled operand layout (both W and X^T), per 128(row) x 32(k) tile = 8 KiB:
//   tile = 512 units of 16B; unit u = kg*128 + r  (kg = (k%32)/8, r = row%128)
//   unit contents = 8 bf16, k = k0 + kg*8 + e.
// ---------------------------------------------------------------------------

// w[o][c] f32 -> wt tiled bf16. 32768 units total.
__global__ __launch_bounds__(256) void conv_w_kernel(
    const float* __restrict__ w, u16* __restrict__ wt) {
  int g = blockIdx.x * 256 + threadIdx.x;  // unit index
  int t_idx = g >> 9;                      // tile index (to*16 + tk)
  int u = g & 511;
  int to = t_idx >> 4, tk = t_idx & 15;
  int r = u & 127, kg = u >> 7;
  int o = to * 128 + r;
  int c = tk * 32 + kg * 8;
  const float4* src = reinterpret_cast<const float4*>(w + (size_t)o * CIN + c);
  float4 lo = src[0], hi = src[1];
  u16x8 pk;
  pk[0] = f2bf(lo.x); pk[1] = f2bf(lo.y); pk[2] = f2bf(lo.z); pk[3] = f2bf(lo.w);
  pk[4] = f2bf(hi.x); pk[5] = f2bf(hi.y); pk[6] = f2bf(hi.z); pk[7] = f2bf(hi.w);
  *reinterpret_cast<u16x8*>(wt + (size_t)g * 8) = pk;
}

// x[b][c][s] f32 -> xt tiled bf16 with (s,c) transpose.
// block = (ts, tk, b): 128 s-cols x 32 c-rows.
__global__ __launch_bounds__(256) void conv_x_kernel(
    const float* __restrict__ x, u16* __restrict__ xt) {
  int ts = blockIdx.x, tk = blockIdx.y, b = blockIdx.z;
  int t = threadIdx.x;
  __shared__ float lf[32 * 128];
  const float* src = x + ((size_t)(b * CIN + tk * 32)) * S_ + ts * 128;
#pragma unroll
  for (int i = 0; i < 4; ++i) {  // 1024 float4 total
    int q = i * 256 + t;
    int c = q >> 5, sq = q & 31;
    *reinterpret_cast<float4*>(&lf[c * 128 + sq * 4]) =
        *reinterpret_cast<const float4*>(src + (size_t)c * S_ + sq * 4);
  }
  __syncthreads();
  size_t tile_base = (((size_t)(b * 32 + ts)) * 16 + tk) * 512;  // in units
#pragma unroll
  for (int i = 0; i < 2; ++i) {
    int u = i * 256 + t;
    int kg = u >> 7, r = u & 127;
    u16x8 pk;
#pragma unroll
    for (int e = 0; e < 8; ++e) pk[e] = f2bf(lf[(kg * 8 + e) * 128 + r]);
    *reinterpret_cast<u16x8*>(xt + (tile_base + u) * 8) = pk;
  }
}

// GEMM: Z[b][o][s] = sum_c W[o][c] * X[b][c][s], 128x128 tile, BK=32,
// 4 waves (2x2), each wave 64x64 = 4x4 frags of mfma_f32_16x16x32_bf16.
__global__ __launch_bounds__(256) void gemm_kernel(
    const u16* __restrict__ wt, const u16* __restrict__ xt,
    u16* __restrict__ z) {
  int nt = blockIdx.x, mt = blockIdx.y, b = blockIdx.z;
  int t = threadIdx.x;
  __shared__ short lds[8192];  // A: bytes [0,8192), B: bytes [8192,16384)
  char* lA = (char*)&lds[0];
  char* lB = lA + 8192;

  int lane = t & 63, wid = t >> 6;
  int wr = wid >> 1, wc = wid & 1;
  int lr = lane & 15, kg = lane >> 4;

  f32x4 acc[4][4];
#pragma unroll
  for (int m = 0; m < 4; ++m)
#pragma unroll
    for (int n = 0; n < 4; ++n) acc[m][n] = f32x4{0.f, 0.f, 0.f, 0.f};

  const char* gA = (const char*)wt + (size_t)(mt * 16) * 8192;
  const char* gB = (const char*)xt + ((size_t)(b * 32 + nt)) * 16 * 8192;

  int abyte[4], bbyte[4];
#pragma unroll
  for (int m = 0; m < 4; ++m) abyte[m] = (kg * 128 + wr * 64 + m * 16 + lr) * 16;
#pragma unroll
  for (int n = 0; n < 4; ++n) bbyte[n] = (kg * 128 + wc * 64 + n * 16 + lr) * 16;

  for (int ks = 0; ks < 16; ++ks) {
    const char* pA = gA + (size_t)ks * 8192;
    const char* pB = gB + (size_t)ks * 8192;
#if HAS_GLOAD
    __syncthreads();  // previous compute done reading LDS
    gload16(pA + t * 16, lA + t * 16);
    gload16(pA + 4096 + t * 16, lA + 4096 + t * 16);
    gload16(pB + t * 16, lB + t * 16);
    gload16(pB + 4096 + t * 16, lB + 4096 + t * 16);
    __syncthreads();  // drains vmcnt, publishes LDS
#else
    u16x8 va0 = *reinterpret_cast<const u16x8*>(pA + t * 16);
    u16x8 va1 = *reinterpret_cast<const u16x8*>(pA + 4096 + t * 16);
    u16x8 vb0 = *reinterpret_cast<const u16x8*>(pB + t * 16);
    u16x8 vb1 = *reinterpret_cast<const u16x8*>(pB + 4096 + t * 16);
    __syncthreads();
    *reinterpret_cast<u16x8*>(lA + t * 16) = va0;
    *reinterpret_cast<u16x8*>(lA + 4096 + t * 16) = va1;
    *reinterpret_cast<u16x8*>(lB + t * 16) = vb0;
    *reinterpret_cast<u16x8*>(lB + 4096 + t * 16) = vb1;
    __syncthreads();
#endif
    bf16x8 av[4], bv[4];
#pragma unroll
    for (int m = 0; m < 4; ++m)
      av[m] = *reinterpret_cast<const bf16x8*>(lA + abyte[m]);
#pragma unroll
    for (int n = 0; n < 4; ++n)
      bv[n] = *reinterpret_cast<const bf16x8*>(lB + bbyte[n]);
#pragma unroll
    for (int m = 0; m < 4; ++m)
#pragma unroll
      for (int n = 0; n < 4; ++n)
        acc[m][n] = __builtin_amdgcn_mfma_f32_16x16x32_bf16(
            av[m], bv[n], acc[m][n], 0, 0, 0);
  }

  // C/D layout: col = lane&15 (s), row = (lane>>4)*4 + reg (o).
  int o_b = mt * 128 + wr * 64 + kg * 4;
  int s_b = nt * 128 + wc * 64 + lr;
#pragma unroll
  for (int m = 0; m < 4; ++m)
#pragma unroll
    for (int n = 0; n < 4; ++n) {
      f32x4 v = acc[m][n];
      size_t base = ((size_t)(b * COUT + o_b + m * 16)) * S_ + (s_b + n * 16);
#pragma unroll
      for (int r = 0; r < 4; ++r) z[base + (size_t)r * S_] = f2bf(v[r]);
    }
}

// R4 upsample: 2 waves per (b,o) image (rows m in [0,32) / [32,64), odd-half
// waves compute a halo h at m0-1). Lane = z column n, owns output cols
// {2n, 2n+1} written as ONE dwordx2 -> fully dense 512B wave stores.
//   h pair: hA = 1*z[m][n-1] + 3*z[m][n]  (tap 0 at n==0)
//           hB = 3*z[m][n]   + 1*z[m][n+1]
//   row 2m-1 = 3*h[m-1] + h[m]  (written by the wave owning m)
//   row 2m   = 1*h[m-1] + 3*h[m]
__global__ __launch_bounds__(256) void upsample_kernel(
    const u16* __restrict__ z, const float* __restrict__ bias,
    float* __restrict__ out) {
  int t = threadIdx.x;
  int lane = t & 63;
  int gw = blockIdx.x * 4 + (t >> 6);  // global wave id
  int bo = gw >> 1;                    // b*512 + o
  int half = gw & 1;
  int m0 = half << 5;

  const u16* zimg = z + ((size_t)bo << 12);
  float bv = bias[bo & 511];
  float* ob = out + (size_t)bo * (HO * WO) + 2 * lane;

  float wl = (lane == 0) ? 0.f : 1.f;  // left-tap mask
  bool has_j1 = (lane < 63);           // col 2n+1 <= 125 valid

  const u16* zp = zimg + (m0 << 6) + lane;
  float hA_p = 0.f, hB_p = 0.f;
  if (half) {  // halo h at row m0-1
    const u16* q = zp - 64;
    float zc = bf2f(q[0]);
    hA_p = fmaf(3.f, zc, bf2f(q[-1]) * wl);
    hB_p = fmaf(3.f, zc, bf2f(q[1]));
  }
  u16 c_ = zp[0], l_ = zp[-1], r_ = zp[1];

#pragma unroll 2
  for (int i = 0; i < 32; ++i) {
    int m = m0 + i;
    float zc = bf2f(c_), zl = bf2f(l_) * wl, zr = bf2f(r_);
    if (m < 63) {  // prefetch next row
      const u16* q = zp + 64;
      c_ = q[0]; l_ = q[-1]; r_ = q[1];
      zp = q;
    }
    float hA = fmaf(3.f, zc, zl);
    float hB = fmaf(3.f, zc, zr);

    float* p_even = ob + (u32)(2 * m) * WO;
    if (m > 0) {  // row 2m-1 = 3*h_prev + h
      float* p_odd = p_even - WO;
      float v0 = fmaf(fmaf(3.f, hA_p, hA), 0.0625f, bv);
      float v1 = fmaf(fmaf(3.f, hB_p, hB), 0.0625f, bv);
      if (has_j1) store2(p_odd, v0, v1); else p_odd[0] = v0;
    }
    {  // row 2m = h_prev + 3*h
      float v0 = fmaf(fmaf(3.f, hA, hA_p), 0.0625f, bv);
      float v1 = fmaf(fmaf(3.f, hB, hB_p), 0.0625f, bv);
      if (has_j1) store2(p_even, v0, v1); else p_even[0] = v0;
    }
    hA_p = hA; hB_p = hB;
  }
}

// Slow but correct fallback if ws_size is insufficient (no workspace needed).
__global__ __launch_bounds__(256) void fallback_kernel(
    const float* __restrict__ x, const float* __restrict__ w,
    const float* __restrict__ bias, float* __restrict__ out) {
  u32 idx = blockIdx.x * 256u + threadIdx.x;
  const u32 total = (u32)B_ * COUT * HO * WO;
  if (idx >= total) return;
  u32 j = idx % WO;
  u32 r1 = idx / WO;
  u32 i = r1 % HO;
  u32 bo = r1 / HO;
  int o = (int)(bo & 511u);
  int b = (int)(bo >> 9);
  int m = (int)(i >> 1), n = (int)(j >> 1);
  int ie = !(i & 1), je = !(j & 1);
  int rA = ie ? m - 1 : m;
  int cA = je ? n - 1 : n;
  float w_r0 = ie ? 1.f : 3.f, w_r1 = ie ? 3.f : 1.f;
  float w_c0 = je ? 1.f : 3.f, w_c1 = je ? 3.f : 1.f;
  const float* xb = x + (size_t)b * CIN * S_;
  float acc = 0.f;
  for (int c = 0; c < CIN; ++c) {
    const float* xc = xb + (size_t)c * S_;
    float y = 0.f;
    if (rA >= 0) {
      if (cA >= 0) y += w_r0 * w_c0 * xc[rA * 64 + cA];
      y += w_r0 * w_c1 * xc[rA * 64 + cA + 1];
    }
    if (cA >= 0) y += w_r1 * w_c0 * xc[(rA + 1) * 64 + cA];
    y += w_r1 * w_c1 * xc[(rA + 1) * 64 + cA + 1];
    acc += y * w[(size_t)o * CIN + c];
  }
  out[idx] = acc * 0.0625f + bias[o];
}

extern "C" void kernel_launch(void* const* d_in, const int* in_sizes, int n_in,
                              void* d_out, int out_size, void* d_ws,
                              size_t ws_size, hipStream_t stream) {
  const float* x = (const float*)d_in[0];
  // d_in[1] = fir_kernel (deterministic, hard-coded taps above)
  const float* w = (const float*)d_in[2];
  const float* bias = (const float*)d_in[3];
  float* out = (float*)d_out;

  const size_t xt_bytes = (size_t)B_ * S_ * CIN * 2;       // 64 MiB
  const size_t wt_off = xt_bytes;
  const size_t wt_bytes = (size_t)COUT * CIN * 2;          // 512 KiB
  const size_t z_off = wt_off + ((wt_bytes + 255) & ~(size_t)255);
  const size_t need = z_off + (size_t)B_ * COUT * S_ * 2;  // ~128.5 MiB
  const size_t total_out = (size_t)B_ * COUT * HO * WO;
  const u32 nblk_out = (u32)((total_out + 255) / 256);

  if (ws_size >= need) {
    u16* xt = (u16*)d_ws;
    u16* wt = (u16*)((char*)d_ws + wt_off);
    u16* zz = (u16*)((char*)d_ws + z_off);
    conv_w_kernel<<<128, 256, 0, stream>>>(w, wt);
    conv_x_kernel<<<dim3(32, 16, B_), 256, 0, stream>>>(x, xt);
    gemm_kernel<<<dim3(32, 4, B_), 256, 0, stream>>>(wt, xt, zz);
    upsample_kernel<<<(B_ * COUT * 2) / 4, 256, 0, stream>>>(zz, bias, out);
  } else {
    fallback_kernel<<<nblk_out, 256, 0, stream>>>(x, w, bias, out);
  }
}